// Round 1
// baseline (334.286 us; speedup 1.0000x reference)
//
#include <hip/hip_runtime.h>
#include <math.h>

#define D_DIM 32000
#define NV4   8000      // D_DIM / 4
#define BLOCK 1024
#define KMAX  8         // ceil(NV4 / BLOCK)
#define CAP   8192      // candidate buffer capacity (32 KB LDS)

// ---- block-wide reduction helpers (16 waves of 64 lanes) ----

__device__ __forceinline__ float blockReduceMax(float v, float* s_tmp, int tid) {
    const int lane = tid & 63;
    const int wid  = tid >> 6;
#pragma unroll
    for (int o = 32; o > 0; o >>= 1) v = fmaxf(v, __shfl_xor(v, o));
    if (lane == 0) s_tmp[wid] = v;
    __syncthreads();
    if (tid < 16) {
        v = s_tmp[tid];
#pragma unroll
        for (int o = 8; o > 0; o >>= 1) v = fmaxf(v, __shfl_xor(v, o));
        if (tid == 0) s_tmp[0] = v;
    }
    __syncthreads();
    v = s_tmp[0];
    __syncthreads();   // s_tmp free for reuse
    return v;
}

__device__ __forceinline__ float4 blockReduceSum4(float4 a, float* s_tmp, int tid) {
    const int lane = tid & 63;
    const int wid  = tid >> 6;
#pragma unroll
    for (int o = 32; o > 0; o >>= 1) {
        a.x += __shfl_xor(a.x, o);
        a.y += __shfl_xor(a.y, o);
        a.z += __shfl_xor(a.z, o);
        a.w += __shfl_xor(a.w, o);
    }
    if (lane == 0) {
        s_tmp[wid * 4 + 0] = a.x; s_tmp[wid * 4 + 1] = a.y;
        s_tmp[wid * 4 + 2] = a.z; s_tmp[wid * 4 + 3] = a.w;
    }
    __syncthreads();
    if (tid < 16) {
        a.x = s_tmp[tid * 4 + 0]; a.y = s_tmp[tid * 4 + 1];
        a.z = s_tmp[tid * 4 + 2]; a.w = s_tmp[tid * 4 + 3];
#pragma unroll
        for (int o = 8; o > 0; o >>= 1) {
            a.x += __shfl_xor(a.x, o);
            a.y += __shfl_xor(a.y, o);
            a.z += __shfl_xor(a.z, o);
            a.w += __shfl_xor(a.w, o);
        }
        if (tid == 0) {
            s_tmp[0] = a.x; s_tmp[1] = a.y; s_tmp[2] = a.z; s_tmp[3] = a.w;
        }
    }
    __syncthreads();
    a.x = s_tmp[0]; a.y = s_tmp[1]; a.z = s_tmp[2]; a.w = s_tmp[3];
    __syncthreads();   // s_tmp free for reuse
    return a;
}

// ---- main kernel: one block per row, row kept in registers ----

__global__ void __launch_bounds__(BLOCK)
entmax_nsect_kernel(const float* __restrict__ X, float* __restrict__ out, int n_rows) {
    const int row = blockIdx.x;
    if (row >= n_rows) return;
    const int tid  = threadIdx.x;
    const int lane = tid & 63;
    const int wid  = tid >> 6;

    __shared__ float s_red[64];      // reduction scratch (16 waves * 4)
    __shared__ float s_cand[CAP];    // compacted candidate values
    __shared__ int   s_wtot[16];     // per-wave candidate totals
    __shared__ int   s_woff[16];     // per-wave exclusive offsets
    __shared__ int   s_cnt;          // total candidate count

    const float4* __restrict__ xrow = reinterpret_cast<const float4*>(X + (size_t)row * D_DIM);
    float4* __restrict__ orow       = reinterpret_cast<float4*>(out + (size_t)row * D_DIM);

    // Phase 1: load row into registers (scaled by alpha-1 = 0.5), track max.
    float4 v[KMAX];
    float mx = -INFINITY;
#pragma unroll
    for (int k = 0; k < KMAX; ++k) {
        int j = tid + k * BLOCK;
        if (j < NV4) {
            float4 t = xrow[j];
            t.x *= 0.5f; t.y *= 0.5f; t.z *= 0.5f; t.w *= 0.5f;
            v[k] = t;
            mx = fmaxf(mx, fmaxf(fmaxf(t.x, t.y), fmaxf(t.z, t.w)));
        } else {
            v[k] = make_float4(-INFINITY, -INFINITY, -INFINITY, -INFINITY);
        }
    }

    const float maxXs = blockReduceMax(mx, s_red, tid);
    float lo = maxXs - 1.0f;
    float hi = maxXs - 0.0055901699437494745f;   // (1/32000)^0.5

    // Phase 2: deterministic compaction of candidates (Xs > lo) into LDS.
    int cntLocal = 0;
#pragma unroll
    for (int k = 0; k < KMAX; ++k) {
        if (v[k].x > lo) cntLocal++;
        if (v[k].y > lo) cntLocal++;
        if (v[k].z > lo) cntLocal++;
        if (v[k].w > lo) cntLocal++;
    }
    // wave-level inclusive scan
    int inc = cntLocal;
#pragma unroll
    for (int o = 1; o < 64; o <<= 1) {
        int y = __shfl_up(inc, o);
        if (lane >= o) inc += y;
    }
    if (lane == 63) s_wtot[wid] = inc;
    __syncthreads();
    if (tid < 16) {
        int w = s_wtot[tid];
        int winc = w;
#pragma unroll
        for (int o = 1; o < 16; o <<= 1) {
            int y = __shfl_up(winc, o);
            if (tid >= o) winc += y;
        }
        s_woff[tid] = winc - w;
        if (tid == 15) s_cnt = winc;
    }
    __syncthreads();
    int pos = s_woff[wid] + (inc - cntLocal);
#pragma unroll
    for (int k = 0; k < KMAX; ++k) {
        if (v[k].x > lo) { if (pos < CAP) s_cand[pos] = v[k].x; pos++; }
        if (v[k].y > lo) { if (pos < CAP) s_cand[pos] = v[k].y; pos++; }
        if (v[k].z > lo) { if (pos < CAP) s_cand[pos] = v[k].z; pos++; }
        if (v[k].w > lo) { if (pos < CAP) s_cand[pos] = v[k].w; pos++; }
    }
    __syncthreads();
    const int  cnt     = s_cnt;
    const bool useRegs = (cnt > CAP);   // correctness fallback; ~never taken

    // Phase 3: 5 rounds of 5-section search, 4 grid points per round.
#pragma unroll 1
    for (int it = 0; it < 5; ++it) {
        const float width = (hi - lo) * 0.2f;
        const float t1 = lo + 1.0f * width;
        const float t2 = lo + 2.0f * width;
        const float t3 = lo + 3.0f * width;
        const float t4 = lo + 4.0f * width;
        float4 acc = make_float4(0.f, 0.f, 0.f, 0.f);
        if (useRegs) {
#pragma unroll
            for (int k = 0; k < KMAX; ++k) {
                float c, d;
                c = v[k].x;
                d = fmaxf(c - t1, 0.f); acc.x = fmaf(d, d, acc.x);
                d = fmaxf(c - t2, 0.f); acc.y = fmaf(d, d, acc.y);
                d = fmaxf(c - t3, 0.f); acc.z = fmaf(d, d, acc.z);
                d = fmaxf(c - t4, 0.f); acc.w = fmaf(d, d, acc.w);
                c = v[k].y;
                d = fmaxf(c - t1, 0.f); acc.x = fmaf(d, d, acc.x);
                d = fmaxf(c - t2, 0.f); acc.y = fmaf(d, d, acc.y);
                d = fmaxf(c - t3, 0.f); acc.z = fmaf(d, d, acc.z);
                d = fmaxf(c - t4, 0.f); acc.w = fmaf(d, d, acc.w);
                c = v[k].z;
                d = fmaxf(c - t1, 0.f); acc.x = fmaf(d, d, acc.x);
                d = fmaxf(c - t2, 0.f); acc.y = fmaf(d, d, acc.y);
                d = fmaxf(c - t3, 0.f); acc.z = fmaf(d, d, acc.z);
                d = fmaxf(c - t4, 0.f); acc.w = fmaf(d, d, acc.w);
                c = v[k].w;
                d = fmaxf(c - t1, 0.f); acc.x = fmaf(d, d, acc.x);
                d = fmaxf(c - t2, 0.f); acc.y = fmaf(d, d, acc.y);
                d = fmaxf(c - t3, 0.f); acc.z = fmaf(d, d, acc.z);
                d = fmaxf(c - t4, 0.f); acc.w = fmaf(d, d, acc.w);
            }
        } else {
            for (int i = tid; i < cnt; i += BLOCK) {
                const float c = s_cand[i];
                float d;
                d = fmaxf(c - t1, 0.f); acc.x = fmaf(d, d, acc.x);
                d = fmaxf(c - t2, 0.f); acc.y = fmaf(d, d, acc.y);
                d = fmaxf(c - t3, 0.f); acc.z = fmaf(d, d, acc.z);
                d = fmaxf(c - t4, 0.f); acc.w = fmaf(d, d, acc.w);
            }
        }
        acc = blockReduceSum4(acc, s_red, tid);
        // f(t) >= 0  <=>  S(t) >= 1 ; apply in order k=1..4 like the reference
        float new_lo = lo;
        if (acc.x >= 1.0f) new_lo = t1;
        if (acc.y >= 1.0f) new_lo = t2;
        if (acc.z >= 1.0f) new_lo = t3;
        if (acc.w >= 1.0f) new_lo = t4;
        lo = new_lo;
        hi = new_lo + width;
    }

    const float tau = 0.5f * (lo + hi);

    // Phase 4: normalizer Z = sum max(Xs - tau, 0)^2 (candidates suffice: tau >= lo)
    float4 zacc = make_float4(0.f, 0.f, 0.f, 0.f);
    if (useRegs) {
#pragma unroll
        for (int k = 0; k < KMAX; ++k) {
            float d;
            d = fmaxf(v[k].x - tau, 0.f); zacc.x = fmaf(d, d, zacc.x);
            d = fmaxf(v[k].y - tau, 0.f); zacc.y = fmaf(d, d, zacc.y);
            d = fmaxf(v[k].z - tau, 0.f); zacc.z = fmaf(d, d, zacc.z);
            d = fmaxf(v[k].w - tau, 0.f); zacc.w = fmaf(d, d, zacc.w);
        }
    } else {
        for (int i = tid; i < cnt; i += BLOCK) {
            const float c = s_cand[i];
            const float d = fmaxf(c - tau, 0.f);
            zacc.x = fmaf(d, d, zacc.x);
        }
    }
    zacc = blockReduceSum4(zacc, s_red, tid);
    const float Z    = zacc.x + zacc.y + zacc.z + zacc.w;
    const float invZ = 1.0f / Z;

    // Phase 5: write output from registers.
#pragma unroll
    for (int k = 0; k < KMAX; ++k) {
        int j = tid + k * BLOCK;
        if (j < NV4) {
            float d;
            float4 p;
            d = fmaxf(v[k].x - tau, 0.f); p.x = d * d * invZ;
            d = fmaxf(v[k].y - tau, 0.f); p.y = d * d * invZ;
            d = fmaxf(v[k].z - tau, 0.f); p.z = d * d * invZ;
            d = fmaxf(v[k].w - tau, 0.f); p.w = d * d * invZ;
            orow[j] = p;
        }
    }
}

extern "C" void kernel_launch(void* const* d_in, const int* in_sizes, int n_in,
                              void* d_out, int out_size, void* d_ws, size_t ws_size,
                              hipStream_t stream) {
    const float* X = (const float*)d_in[0];
    float* out     = (float*)d_out;
    const int n_rows = in_sizes[0] / D_DIM;   // 4096
    entmax_nsect_kernel<<<dim3(n_rows), dim3(BLOCK), 0, stream>>>(X, out, n_rows);
}

// Round 3
// 251.657 us; speedup vs baseline: 1.3283x; 1.3283x over previous
//
#include <hip/hip_runtime.h>
#include <math.h>

#define D_DIM 32000
#define NV4   8000      // D_DIM / 4
#define BLOCK 1024
#define KMAX  8         // NV4 / BLOCK (rounded up)
#define NBINS      3125 // 5^5 lattice cells of the n-section
#define NBINS_PAD  4096

// lattice over y = Xs - max(Xs), interval [-1, -(1/32000)^0.5], width W0
#define W0_F     0.9944098300562505
#define BINW_F   3.182111456180002e-4f   // W0/3125
#define INVBW_F  3142.5681f              // 3125/W0

typedef float floatx4 __attribute__((ext_vector_type(4)));   // native vec for nontemporal store

// ---- block-wide reduction helpers (16 waves of 64 lanes) ----

__device__ __forceinline__ float blockReduceMax(float v, float* s_tmp, int tid) {
    const int lane = tid & 63;
    const int wid  = tid >> 6;
#pragma unroll
    for (int o = 32; o > 0; o >>= 1) v = fmaxf(v, __shfl_xor(v, o));
    if (lane == 0) s_tmp[wid] = v;
    __syncthreads();
    if (tid < 16) {
        v = s_tmp[tid];
#pragma unroll
        for (int o = 8; o > 0; o >>= 1) v = fmaxf(v, __shfl_xor(v, o));
        if (tid == 0) s_tmp[0] = v;
    }
    __syncthreads();
    v = s_tmp[0];
    __syncthreads();
    return v;
}

__device__ __forceinline__ float4 blockReduceSum4(float4 a, float* s_tmp, int tid) {
    const int lane = tid & 63;
    const int wid  = tid >> 6;
#pragma unroll
    for (int o = 32; o > 0; o >>= 1) {
        a.x += __shfl_xor(a.x, o);
        a.y += __shfl_xor(a.y, o);
        a.z += __shfl_xor(a.z, o);
        a.w += __shfl_xor(a.w, o);
    }
    if (lane == 0) {
        s_tmp[wid * 4 + 0] = a.x; s_tmp[wid * 4 + 1] = a.y;
        s_tmp[wid * 4 + 2] = a.z; s_tmp[wid * 4 + 3] = a.w;
    }
    __syncthreads();
    if (tid < 16) {
        a.x = s_tmp[tid * 4 + 0]; a.y = s_tmp[tid * 4 + 1];
        a.z = s_tmp[tid * 4 + 2]; a.w = s_tmp[tid * 4 + 3];
#pragma unroll
        for (int o = 8; o > 0; o >>= 1) {
            a.x += __shfl_xor(a.x, o);
            a.y += __shfl_xor(a.y, o);
            a.z += __shfl_xor(a.z, o);
            a.w += __shfl_xor(a.w, o);
        }
        if (tid == 0) {
            s_tmp[0] = a.x; s_tmp[1] = a.y; s_tmp[2] = a.z; s_tmp[3] = a.w;
        }
    }
    __syncthreads();
    a.x = s_tmp[0]; a.y = s_tmp[1]; a.z = s_tmp[2]; a.w = s_tmp[3];
    __syncthreads();
    return a;
}

// ---- main kernel: one block per row, row in registers, histogram n-section ----

__global__ void __launch_bounds__(BLOCK)
entmax_nsect_kernel(const float* __restrict__ X, float* __restrict__ out, int n_rows) {
    const int row = blockIdx.x;
    if (row >= n_rows) return;
    const int tid  = threadIdx.x;
    const int lane = tid & 63;
    const int wid  = tid >> 6;

    __shared__ float s_red[64];          // reduction scratch
    __shared__ float s_wv[48];           // 16 wave totals x 3 moments (scan stage)
    __shared__ float sC[NBINS_PAD];      // count  -> suffix count
    __shared__ float sS[NBINS_PAD];      // sum    -> suffix sum
    __shared__ float sQ[NBINS_PAD];      // sumsq  -> suffix sumsq

    const float4* __restrict__ xrow = reinterpret_cast<const float4*>(X + (size_t)row * D_DIM);
    floatx4* __restrict__ orow      = reinterpret_cast<floatx4*>(out + (size_t)row * D_DIM);

    // Phase 1: load row into registers (scaled by alpha-1 = 0.5), zero LDS, max.
    float4 v[KMAX];
    float mx = -INFINITY;
#pragma unroll
    for (int k = 0; k < KMAX; ++k) {
        int j = tid + k * BLOCK;
        if (j < NV4) {
            float4 t = xrow[j];
            t.x *= 0.5f; t.y *= 0.5f; t.z *= 0.5f; t.w *= 0.5f;
            v[k] = t;
        } else {
            v[k] = make_float4(-INFINITY, -INFINITY, -INFINITY, -INFINITY);
        }
    }
    {   // zero histogram planes (overlaps with outstanding loads)
        const float4 z4 = make_float4(0.f, 0.f, 0.f, 0.f);
        reinterpret_cast<float4*>(sC)[tid] = z4;
        reinterpret_cast<float4*>(sS)[tid] = z4;
        reinterpret_cast<float4*>(sQ)[tid] = z4;
    }
#pragma unroll
    for (int k = 0; k < KMAX; ++k)
        mx = fmaxf(mx, fmaxf(fmaxf(v[k].x, v[k].y), fmaxf(v[k].z, v[k].w)));

    const float maxXs = blockReduceMax(mx, s_red, tid);
    // (blockReduceMax's internal barriers also order the LDS zeroing above)

    // Phase 2: moment histogram over y = Xs - max, candidates y > -1.
#pragma unroll
    for (int k = 0; k < KMAX; ++k) {
        float ys[4] = { v[k].x - maxXs, v[k].y - maxXs, v[k].z - maxXs, v[k].w - maxXs };
#pragma unroll
        for (int c = 0; c < 4; ++c) {
            float y = ys[c];
            if (y > -1.0f) {
                int b = (int)fminf((y + 1.0f) * INVBW_F, 3124.0f);
                atomicAdd(&sC[b], 1.0f);
                atomicAdd(&sS[b], y);
                atomicAdd(&sQ[b], y * y);
            }
        }
    }
    __syncthreads();

    // Phase 3: in-place suffix scan -> SUF[k] = sum over bins >= k, per moment.
    float4 c4 = reinterpret_cast<const float4*>(sC)[tid];
    float4 s4 = reinterpret_cast<const float4*>(sS)[tid];
    float4 q4 = reinterpret_cast<const float4*>(sQ)[tid];
    const float cT = c4.x + c4.y + c4.z + c4.w;
    const float sT = s4.x + s4.y + s4.z + s4.w;
    const float qT = q4.x + q4.y + q4.z + q4.w;
    // wave-level inclusive suffix scan (sum over lanes >= lane)
    float ci = cT, si = sT, qi = qT;
#pragma unroll
    for (int o = 1; o < 64; o <<= 1) {
        float a = __shfl_down(ci, o);
        float b = __shfl_down(si, o);
        float c = __shfl_down(qi, o);
        if (lane + o < 64) { ci += a; si += b; qi += c; }
    }
    if (lane == 0) { s_wv[wid] = ci; s_wv[16 + wid] = si; s_wv[32 + wid] = qi; }
    __syncthreads();
    if (tid < 16) {
        float wc = s_wv[tid], ws = s_wv[16 + tid], wq = s_wv[32 + tid];
        const float oc = wc, os = ws, oq = wq;
#pragma unroll
        for (int o = 1; o < 16; o <<= 1) {
            float a = __shfl_down(wc, o);
            float b = __shfl_down(ws, o);
            float c = __shfl_down(wq, o);
            if (tid + o < 16) { wc += a; ws += b; wq += c; }
        }
        // exclusive suffix from waves above this one
        s_wv[tid] = wc - oc; s_wv[16 + tid] = ws - os; s_wv[32 + tid] = wq - oq;
    }
    __syncthreads();
    {
        const float ac = s_wv[wid] + (ci - cT);
        const float as = s_wv[16 + wid] + (si - sT);
        const float aq = s_wv[32 + wid] + (qi - qT);
        float4 co, so, qo;
        co.w = ac + c4.w; co.z = co.w + c4.z; co.y = co.z + c4.y; co.x = co.y + c4.x;
        so.w = as + s4.w; so.z = so.w + s4.z; so.y = so.z + s4.y; so.x = so.y + s4.x;
        qo.w = aq + q4.w; qo.z = qo.w + q4.z; qo.y = qo.z + q4.y; qo.x = qo.y + q4.x;
        reinterpret_cast<float4*>(sC)[tid] = co;
        reinterpret_cast<float4*>(sS)[tid] = so;
        reinterpret_cast<float4*>(sQ)[tid] = qo;
    }
    __syncthreads();

    // Phase 4: n-section entirely via table lookups (no barriers, all threads redundant).
    // f(t) >= 0  <=>  SS - 2 t S + t^2 C >= 1  at lattice boundary t_k = -1 + k*binw.
    int lo_idx = 0;
    int w = 625;
#pragma unroll
    for (int it = 0; it < 5; ++it) {
        int nl = lo_idx;
#pragma unroll
        for (int j = 1; j <= 4; ++j) {
            const int k = lo_idx + j * w;
            const float t  = fmaf((float)k, BINW_F, -1.0f);
            const float Ck = sC[k];
            const float Sk = sS[k];
            const float Qk = sQ[k];
            const float ssum = fmaf(t, fmaf(t, Ck, -2.0f * Sk), Qk);
            if (ssum >= 1.0f) nl = k;
        }
        lo_idx = nl;
        w /= 5;
    }
    const float tau = maxXs + fmaf((float)lo_idx + 0.5f, BINW_F, -1.0f);

    // Phase 5: exact normalizer from registers (one reduction).
    float4 zacc = make_float4(0.f, 0.f, 0.f, 0.f);
#pragma unroll
    for (int k = 0; k < KMAX; ++k) {
        float d;
        d = fmaxf(v[k].x - tau, 0.f); zacc.x = fmaf(d, d, zacc.x);
        d = fmaxf(v[k].y - tau, 0.f); zacc.y = fmaf(d, d, zacc.y);
        d = fmaxf(v[k].z - tau, 0.f); zacc.z = fmaf(d, d, zacc.z);
        d = fmaxf(v[k].w - tau, 0.f); zacc.w = fmaf(d, d, zacc.w);
    }
    zacc = blockReduceSum4(zacc, s_red, tid);
    const float invZ = 1.0f / (zacc.x + zacc.y + zacc.z + zacc.w);

    // Phase 6: write output from registers (non-temporal: don't evict X from L3).
#pragma unroll
    for (int k = 0; k < KMAX; ++k) {
        int j = tid + k * BLOCK;
        if (j < NV4) {
            float d;
            floatx4 p;
            d = fmaxf(v[k].x - tau, 0.f); p.x = d * d * invZ;
            d = fmaxf(v[k].y - tau, 0.f); p.y = d * d * invZ;
            d = fmaxf(v[k].z - tau, 0.f); p.z = d * d * invZ;
            d = fmaxf(v[k].w - tau, 0.f); p.w = d * d * invZ;
            __builtin_nontemporal_store(p, &orow[j]);
        }
    }
}

extern "C" void kernel_launch(void* const* d_in, const int* in_sizes, int n_in,
                              void* d_out, int out_size, void* d_ws, size_t ws_size,
                              hipStream_t stream) {
    const float* X = (const float*)d_in[0];
    float* out     = (float*)d_out;
    const int n_rows = in_sizes[0] / D_DIM;   // 4096
    entmax_nsect_kernel<<<dim3(n_rows), dim3(BLOCK), 0, stream>>>(X, out, n_rows);
}